// Round 6
// baseline (69.584 us; speedup 1.0000x reference)
//
#include <hip/hip_runtime.h>
#include <cstdint>
#include <math.h>

#define NPARTS 4
#define NPTS   8192
#define YSPLIT 8
#define XT     64          // 8192 / 128 rows per block

// ws layout (bytes)
#define WS_SUMS_OFF 0                         // double[10]
#define WS_T_OFF    128                       // float[4][16]
#define KVB_OFF     1024                      // uint4[2 set][4 p][2 half][8192]  = 2 MiB
#define PTS_OFF     (KVB_OFF + 2097152)       // float4[2 set][4 p][8192]         = 1 MiB
#define PART_OFF    (PTS_OFF + 1048576)       // float[2 dir][4 p][YSPLIT][8192]  = 2 MiB

typedef __bf16 bf16x8 __attribute__((ext_vector_type(8)));
typedef float  f32x4  __attribute__((ext_vector_type(4)));
typedef float  f32x16 __attribute__((ext_vector_type(16)));

__device__ __forceinline__ float min3f(float a, float b, float c) {
    float d;
    asm("v_min3_f32 %0, %1, %2, %3" : "=v"(d) : "v"(a), "v"(b), "v"(c));
    return d;
}

__device__ __forceinline__ void make_T(const float* __restrict__ rq,
                                       const float* __restrict__ tras,
                                       int p, float* T) {
    float q0 = rq[p*4+0], q1 = rq[p*4+1], q2 = rq[p*4+2], q3 = rq[p*4+3];
    float inv = 1.0f / sqrtf(q0*q0 + q1*q1 + q2*q2 + q3*q3);
    float a = q0*inv, b = q1*inv, c = q2*inv, d = q3*inv;
    T[0]  = 1.f - 2.f*c*c - 2.f*d*d;
    T[1]  = 2.f*b*c - 2.f*a*d;
    T[2]  = 2.f*a*c + 2.f*b*d;
    T[3]  = tras[p*3+0];
    T[4]  = 2.f*b*c + 2.f*a*d;
    T[5]  = 1.f - 2.f*b*b - 2.f*d*d;
    T[6]  = 2.f*c*d - 2.f*a*b;
    T[7]  = tras[p*3+1];
    T[8]  = 2.f*b*d - 2.f*a*c;
    T[9]  = 2.f*a*b + 2.f*c*d;
    T[10] = 1.f - 2.f*b*b - 2.f*c*c;
    T[11] = tras[p*3+2];
}

// Build f32 point buffer + split-bf16 B-side k-vectors for both sets.
// set 0 = transformed cad, set 1 = raw cam. Also transforms -> ws/out, E_kin distance sum.
__global__ __launch_bounds__(256) void k_pre(const float* __restrict__ cam,
                                             const float* __restrict__ cad,
                                             const float* __restrict__ rq,
                                             const float* __restrict__ tras,
                                             float* __restrict__ ws,
                                             float* __restrict__ out) {
    int gid = blockIdx.x * 256 + threadIdx.x;      // 0..65535
    int set = gid >> 15;
    int p   = (gid >> 13) & 3;
    int i   = gid & (NPTS - 1);

    float T[12];
    make_T(rq, tras, p, T);

    float w0, w1, w2;
    float c0 = 0.f, c1 = 0.f, c2 = 0.f;
    if (set == 0) {
        float v0 = cad[(size_t)(p*NPTS + i)*3 + 0];
        float v1 = cad[(size_t)(p*NPTS + i)*3 + 1];
        float v2 = cad[(size_t)(p*NPTS + i)*3 + 2];
        w0 = fmaf(T[0], v0, fmaf(T[1], v1, fmaf(T[2],  v2, T[3])));
        w1 = fmaf(T[4], v0, fmaf(T[5], v1, fmaf(T[6],  v2, T[7])));
        w2 = fmaf(T[8], v0, fmaf(T[9], v1, fmaf(T[10], v2, T[11])));
        c0 = cam[(size_t)(p*NPTS + i)*3 + 0];
        c1 = cam[(size_t)(p*NPTS + i)*3 + 1];
        c2 = cam[(size_t)(p*NPTS + i)*3 + 2];
    } else {
        w0 = cam[(size_t)(p*NPTS + i)*3 + 0];
        w1 = cam[(size_t)(p*NPTS + i)*3 + 1];
        w2 = cam[(size_t)(p*NPTS + i)*3 + 2];
    }

    float Xs = w0*w0 + w1*w1 + w2*w2;

    f32x4* pts = (f32x4*)((char*)ws + PTS_OFF);
    size_t sp = (size_t)(set*4 + p);
    pts[sp*NPTS + i] = (f32x4){w0, w1, w2, Xs};

    __bf16 h0 = (__bf16)w0, h1 = (__bf16)w1, h2 = (__bf16)w2;
    __bf16 l0 = (__bf16)(w0 - (float)h0);
    __bf16 l1 = (__bf16)(w1 - (float)h1);
    __bf16 l2 = (__bf16)(w2 - (float)h2);
    __bf16 sh = (__bf16)Xs;
    __bf16 sl = (__bf16)(Xs - (float)sh);
    __bf16 one = (__bf16)1.0f;

    // B k-vector: [yh0..2, yl0..2, yh0..1 | yh2, yl0..2, 1, 1, Ysh, Ysl]
    bf16x8 B0 = {h0, h1, h2, l0, l1, l2, h0, h1};
    bf16x8 B1 = {h2, l0, l1, l2, one, one, sh, sl};

    uint4* kvb = (uint4*)((char*)ws + KVB_OFF);
    kvb[(sp*2 + 0)*NPTS + i] = __builtin_bit_cast(uint4, B0);
    kvb[(sp*2 + 1)*NPTS + i] = __builtin_bit_cast(uint4, B1);

    if (blockIdx.x == 0 && threadIdx.x < 4) {
        float Tt[12];
        make_T(rq, tras, threadIdx.x, Tt);
        float* wsT = ws + WS_T_OFF/4 + threadIdx.x*16;
        float* outT = out + 6 + threadIdx.x*16;
        #pragma unroll
        for (int k = 0; k < 12; ++k) { wsT[k] = Tt[k]; outT[k] = Tt[k]; }
        wsT[12] = 0.f; wsT[13] = 0.f; wsT[14] = 0.f; wsT[15] = 1.f;
        outT[12] = 0.f; outT[13] = 0.f; outT[14] = 0.f; outT[15] = 1.f;
    }

    // E_kin paired-distance term (set 0 blocks only; w-components cancel)
    if (set == 0) {
        float d0 = w0 - c0, d1 = w1 - c1, d2 = w2 - c2;
        double local = sqrt((double)(d0*d0 + d1*d1 + d2*d2));
        __shared__ double red[256];
        red[threadIdx.x] = local;
        __syncthreads();
        for (int s = 128; s > 0; s >>= 1) {
            if (threadIdx.x < s) red[threadIdx.x] += red[threadIdx.x + s];
            __syncthreads();
        }
        if (threadIdx.x == 0)
            atomicAdd((double*)((char*)ws + WS_SUMS_OFF) + 8, red[0]);
    }
}

// MFMA chamfer (selection only): one v_mfma_f32_32x32x16_bf16 per 32x32 tile gives
// split-precision d2; y-index packed into low 13 mantissa bits; v_min3 carries argmin.
// Block = 4 waves x 32 rows = 128 rows; y-window = 1024 cols staged in LDS.
// grid = 2 dir x 4 p x 64 xt x 8 ys = 4096 blocks.
__global__ __launch_bounds__(256, 2) void k_chamfer(float* __restrict__ ws) {
    const int tid  = threadIdx.x;
    const int lane = tid & 63;
    const int wv   = tid >> 6;
    const int col  = lane & 31;
    const int half = lane >> 5;

    const int b   = blockIdx.x;
    const int ys  = b & (YSPLIT - 1);
    const int xt  = (b >> 3) & (XT - 1);
    const int p   = (b >> 9) & 3;
    const int dir = b >> 11;
    const int setA = dir;            // dir0: rows=cadT(set0); dir1: rows=cam(set1)
    const int setB = 1 - dir;

    __shared__ uint4 ywin[2048];     // [half][1024 cols] : 32 KiB

    const uint4* kvb = (const uint4*)((const char*)ws + KVB_OFF) + ((size_t)(setB*4 + p)*2)*NPTS;
    const f32x4* ptsA = (const f32x4*)((const char*)ws + PTS_OFF) + (size_t)(setA*4 + p)*NPTS;
    const int ywin0 = ys * 1024;

    for (int i = tid; i < 2048; i += 256) {
        int h = i >> 10, c = i & 1023;
        ywin[i] = kvb[(size_t)h*NPTS + ywin0 + c];
    }

    // build this lane's A fragment from the f32 point
    const int rowbase = xt*128 + wv*32;
    bf16x8 af;
    {
        f32x4 X = ptsA[rowbase + col];
        float w0 = X.x, w1 = X.y, w2 = X.z, Xs = X.w;
        __bf16 h0 = (__bf16)w0, h1 = (__bf16)w1, h2 = (__bf16)w2;
        __bf16 l0 = (__bf16)(w0 - (float)h0);
        __bf16 l1 = (__bf16)(w1 - (float)h1);
        __bf16 l2 = (__bf16)(w2 - (float)h2);
        __bf16 sh = (__bf16)Xs;
        __bf16 sl = (__bf16)(Xs - (float)sh);
        __bf16 one = (__bf16)1.0f;
        __bf16 m0 = (__bf16)(-2.f*(float)h0), m1 = (__bf16)(-2.f*(float)h1), m2 = (__bf16)(-2.f*(float)h2);
        __bf16 n0 = (__bf16)(-2.f*(float)l0), n1 = (__bf16)(-2.f*(float)l1), n2 = (__bf16)(-2.f*(float)l2);
        // A k-vector: [-2xh0..2, -2xh0..2, -2xl0..1 | -2xl2, -2xl0..2, Xsh, Xsl, 1, 1]
        bf16x8 A0 = {m0, m1, m2, m0, m1, m2, n0, n1};
        bf16x8 A1 = {n2, n0, n1, n2, sh, sl, one, one};
        af = half ? A1 : A0;
    }

    f32x16 Z = {0,0,0,0,0,0,0,0,0,0,0,0,0,0,0,0};
    float rm[16];
    #pragma unroll
    for (int i = 0; i < 16; ++i) rm[i] = INFINITY;

    __syncthreads();

    const int hbase = half * 1024;
    const uint32_t ipack0 = (uint32_t)(ywin0 + col);
    #pragma unroll 4
    for (int s = 0; s < 32; s += 2) {
        bf16x8 b0 = __builtin_bit_cast(bf16x8, ywin[hbase + (s+0)*32 + col]);
        bf16x8 b1 = __builtin_bit_cast(bf16x8, ywin[hbase + (s+1)*32 + col]);
        f32x16 a0 = __builtin_amdgcn_mfma_f32_32x32x16_bf16(af, b0, Z, 0, 0, 0);
        f32x16 a1 = __builtin_amdgcn_mfma_f32_32x32x16_bf16(af, b1, Z, 0, 0, 0);
        const uint32_t i0 = ipack0 + (uint32_t)(s*32);
        const uint32_t i1 = i0 + 32u;
        #pragma unroll
        for (int i = 0; i < 16; ++i) {
            uint32_t u0 = (__float_as_uint(a0[i]) & 0xFFFFE000u) | i0;
            uint32_t u1 = (__float_as_uint(a1[i]) & 0xFFFFE000u) | i1;
            rm[i] = min3f(rm[i], __uint_as_float(u0), __uint_as_float(u1));
        }
    }

    // reduce each rm over the 32 lanes of this half-wave (butterfly)
    #pragma unroll
    for (int m = 1; m <= 16; m <<= 1) {
        #pragma unroll
        for (int i = 0; i < 16; ++i)
            rm[i] = fminf(rm[i], __shfl_xor(rm[i], m, 64));
    }

    if (col == 0) {
        float* rowpart = (float*)((char*)ws + PART_OFF) + ((size_t)((dir*4 + p)*YSPLIT + ys))*NPTS + rowbase;
        #pragma unroll
        for (int i = 0; i < 16; ++i) {
            int row = (i & 3) + 8*(i >> 2) + 4*half;   // 32x32 C layout (m74/m101)
            rowpart[row] = rm[i];
        }
    }
}

// combine packed partials -> extract argmin -> exact f64 recompute -> sum of distances
__global__ __launch_bounds__(256) void k_reduce(float* __restrict__ ws) {
    __shared__ double red[256];
    const int b = blockIdx.x;          // 64 blocks
    const int tid = threadIdx.x;
    const int dir = b >> 5, p = (b >> 3) & 3, seg = b & 7;
    const int setA = dir, setB = 1 - dir;
    const float* part = (const float*)((const char*)ws + PART_OFF) + ((size_t)(dir*4 + p))*YSPLIT*NPTS;
    const f32x4* pts  = (const f32x4*)((const char*)ws + PTS_OFF);
    const f32x4* xp = pts + (size_t)(setA*4 + p)*NPTS;
    const f32x4* ypt = pts + (size_t)(setB*4 + p)*NPTS;
    double local = 0.0;
    #pragma unroll
    for (int k = 0; k < 4; ++k) {
        int row = seg*1024 + k*256 + tid;
        float m = INFINITY;
        #pragma unroll
        for (int y = 0; y < YSPLIT; ++y)
            m = fminf(m, part[(size_t)y*NPTS + row]);
        uint32_t idx = __float_as_uint(m) & 0x1FFFu;
        f32x4 X = xp[row];
        f32x4 Y = ypt[idx];
        double d0 = (double)X.x - (double)Y.x;
        double d1 = (double)X.y - (double)Y.y;
        double d2 = (double)X.z - (double)Y.z;
        local += sqrt(fmax(d0*d0 + d1*d1 + d2*d2, 0.0));
    }
    red[tid] = local;
    __syncthreads();
    for (int s = 128; s > 0; s >>= 1) {
        if (tid < s) red[tid] += red[tid + s];
        __syncthreads();
    }
    if (tid == 0)
        atomicAdd((double*)((char*)ws + WS_SUMS_OFF) + p*2 + dir, red[0]);
}

__global__ void k_final(const float* __restrict__ pw,
                        const float* __restrict__ rtk,
                        const float* __restrict__ ja,
                        const float* __restrict__ ws,
                        float* __restrict__ out) {
    const double* sums = (const double*)((const char*)ws + WS_SUMS_OFF);
    const float* Tw = ws + WS_T_OFF/4;
    double eners[NPARTS];
    for (int p = 0; p < NPARTS; ++p)
        eners[p] = 5.0 * ((sums[p*2+0] + sums[p*2+1]) / (double)NPTS);

    double mn = eners[0], mx = eners[0];
    for (int p = 1; p < NPARTS; ++p) { mn = fmin(mn, eners[p]); mx = fmax(mx, eners[p]); }
    double et[NPARTS], etmax = -1e300;
    for (int p = 0; p < NPARTS; ++p) { et[p] = (eners[p] - mn) / (mx - mn + 1e-8); etmax = fmax(etmax, et[p]); }
    double ex[NPARTS], se = 0.0;
    for (int p = 0; p < NPARTS; ++p) { ex[p] = exp(et[p] - etmax); se += ex[p]; }

    double ep[NPARTS], all_obj = 0.0, epmax = -1e300;
    for (int p = 0; p < NPARTS; ++p) {
        double sm = ex[p] / se;
        ep[p] = (double)pw[p] * sm * eners[p];
        all_obj += sm * eners[p];
        epmax = fmax(epmax, ep[p]);
    }

    double distances = sums[8] / (double)(NPARTS * NPTS);

    double v[4], Tj[4], ss = 0.0;
    for (int i = 0; i < 4; ++i) {
        v[i] = 0.0;
        for (int k = 0; k < 4; ++k) v[i] += (double)Tw[0*16 + i*4 + k] * (double)ja[0*8 + 0*4 + k];
    }
    for (int i = 0; i < 4; ++i) {
        Tj[i] = 0.0;
        for (int k = 0; k < 4; ++k) Tj[i] += (double)rtk[0*16 + i*4 + k] * v[k];
    }
    for (int q = 1; q < NPARTS; ++q) {
        double vv[4], u[4];
        for (int i = 0; i < 4; ++i) {
            vv[i] = 0.0;
            for (int k = 0; k < 4; ++k) vv[i] += (double)Tw[q*16 + i*4 + k] * (double)ja[(q-1)*8 + 4 + k];
        }
        for (int i = 0; i < 4; ++i) {
            u[i] = 0.0;
            for (int k = 0; k < 4; ++k) u[i] += (double)rtk[q*16 + i*4 + k] * vv[k];
        }
        for (int i = 0; i < 3; ++i) { double dd = Tj[i] - u[i]; ss += dd * dd; }
    }
    double nrm = sqrt(ss) / (double)NPARTS;
    double e_kin = log(0.1 * nrm + 1.0) + distances;
    double ekt = epmax * e_kin;
    all_obj += ekt;

    out[0] = (float)all_obj;
    for (int p = 0; p < NPARTS; ++p) out[1 + p] = (float)ep[p];
    out[5] = (float)ekt;
}

extern "C" void kernel_launch(void* const* d_in, const int* in_sizes, int n_in,
                              void* d_out, int out_size, void* d_ws, size_t ws_size,
                              hipStream_t stream) {
    const float* cam  = (const float*)d_in[0];
    const float* cad  = (const float*)d_in[1];
    const float* pw   = (const float*)d_in[2];
    const float* rq   = (const float*)d_in[3];
    const float* tras = (const float*)d_in[4];
    const float* rtk  = (const float*)d_in[5];
    const float* ja   = (const float*)d_in[6];
    float* out = (float*)d_out;
    float* ws  = (float*)d_ws;

    hipMemsetAsync(ws, 0, 128, stream);
    hipLaunchKernelGGL(k_pre,     dim3(256),  dim3(256), 0, stream, cam, cad, rq, tras, ws, out);
    hipLaunchKernelGGL(k_chamfer, dim3(4096), dim3(256), 0, stream, ws);
    hipLaunchKernelGGL(k_reduce,  dim3(64),   dim3(256), 0, stream, ws);
    hipLaunchKernelGGL(k_final,   dim3(1),    dim3(1),   0, stream, pw, rtk, ja, ws, out);
}